// Round 1
// baseline (1064.169 us; speedup 1.0000x reference)
//
#include <hip/hip_runtime.h>

#define DIM 128
typedef unsigned char u8;

// ---------------- MLP grid evaluation: one thread = one point ----------------
__global__ __launch_bounds__(256) void eval_grid_kernel(
    const float* __restrict__ W1, const float* __restrict__ b1,
    const float* __restrict__ W2, const float* __restrict__ b2,
    const float* __restrict__ W3, const float* __restrict__ b3,
    const float* __restrict__ bmin, const float* __restrict__ bmax,
    float* __restrict__ out, int R)
{
    int idx = blockIdx.x * blockDim.x + threadIdx.x;
    int N = R * R;
    if (idx >= N) return;
    int i = idx / R;
    int j = idx - i * R;
    float inv = 1.0f / (float)(R - 1);   // R-1 is a power of two -> exact
    float u = (float)j * inv;
    float v = (float)i * inv;
    float x = bmin[0] + u * (bmax[0] - bmin[0]);
    float y = bmin[1] + v * (bmax[1] - bmin[1]);

    float acc[DIM];
    #pragma unroll
    for (int t = 0; t < DIM; t++) acc[t] = b2[t];

    #pragma unroll 2
    for (int k = 0; k < DIM; k++) {
        float pre = x * W1[k] + y * W1[DIM + k] + b1[k];
        float h = tanhf(pre);
        const float* w2row = W2 + k * DIM;   // wave-uniform address -> s_load
        #pragma unroll
        for (int t = 0; t < DIM; t++) acc[t] = fmaf(h, w2row[t], acc[t]);
    }
    float o = b3[0];
    #pragma unroll
    for (int t = 0; t < DIM; t++) o += tanhf(acc[t]) * W3[t];
    out[idx] = 1.0f / (1.0f + expf(-o));
}

// ------------- per level: exact 2x-1 bilinear upsample + raw boundary --------
__global__ __launch_bounds__(256) void init_level_kernel(
    const float* __restrict__ occP, int Rp,
    float* __restrict__ occI, u8* __restrict__ raw, int R)
{
    int idx = blockIdx.x * blockDim.x + threadIdx.x;
    int N = R * R;
    if (idx >= N) return;
    int i = idx / R;
    int j = idx - i * R;
    int ip = i >> 1, jp = j >> 1;
    const float BAL = 0.5f;
    float tl = occP[ip * Rp + jp];
    float val; bool b;
    int oi = i & 1, oj = j & 1;
    if (!oi && !oj) {
        val = tl; b = false;
    } else if (oi && !oj) {
        float bl = occP[(ip + 1) * Rp + jp];
        val = 0.5f * (tl + bl);
        b = (tl > BAL) != (bl > BAL);
    } else if (!oi && oj) {
        float tr = occP[ip * Rp + jp + 1];
        val = 0.5f * (tl + tr);
        b = (tl > BAL) != (tr > BAL);
    } else {
        float bl = occP[(ip + 1) * Rp + jp];
        float tr = occP[ip * Rp + jp + 1];
        float br = occP[(ip + 1) * Rp + jp + 1];
        val = 0.5f * (0.5f * (tl + bl) + 0.5f * (tr + br));  // exact _up2 order
        bool m0 = tl > BAL, m1 = bl > BAL, m2 = tr > BAL, m3 = br > BAL;
        b = (m0 | m1 | m2 | m3) && !(m0 & m1 & m2 & m3);
    }
    occI[idx] = val;
    raw[idx] = b ? 1 : 0;
}

// ------- boundary = any3x3(raw) & ~calc ; conflicts ; occ select ; calc ------
__global__ __launch_bounds__(256) void boundary_resolve_kernel(
    const u8* __restrict__ raw, const u8* __restrict__ calcP, int Rp,
    const float* __restrict__ q, float* __restrict__ occ,
    u8* __restrict__ calc, u8* __restrict__ conf, int R)
{
    int idx = blockIdx.x * blockDim.x + threadIdx.x;
    int N = R * R;
    if (idx >= N) return;
    int i = idx / R;
    int j = idx - i * R;
    bool b = false;
    for (int di = -1; di <= 1; di++) {
        int ii = i + di;
        if (ii < 0 || ii >= R) continue;
        for (int dj = -1; dj <= 1; dj++) {
            int jj = j + dj;
            if (jj < 0 || jj >= R) continue;
            if (raw[ii * R + jj]) b = true;
        }
    }
    bool c0 = (((i | j) & 1) == 0) ? (calcP[(i >> 1) * Rp + (j >> 1)] != 0) : false;
    b = b && !c0;
    float oi = occ[idx];
    float qq = q[idx];
    bool cf = b && ((oi - 0.5f) * (qq - 0.5f) < 0.0f);
    occ[idx] = b ? qq : oi;
    calc[idx] = (c0 || b) ? 1 : 0;
    conf[idx] = cf ? 1 : 0;
}

// --------------------- one conflict propagation iteration --------------------
__global__ __launch_bounds__(256) void conflict_iter_kernel(
    const u8* __restrict__ cin, u8* __restrict__ cout,
    u8* __restrict__ calc, const float* __restrict__ q,
    float* __restrict__ occ, int R)
{
    int idx = blockIdx.x * blockDim.x + threadIdx.x;
    int N = R * R;
    if (idx >= N) return;
    int i = idx / R;
    int j = idx - i * R;
    bool any = false;
    for (int di = -1; di <= 1; di++) {
        int ii = i + di;
        if (ii < 0 || ii >= R) continue;
        for (int dj = -1; dj <= 1; dj++) {
            int jj = j + dj;
            if (jj < 0 || jj >= R) continue;
            if (cin[ii * R + jj]) any = true;
        }
    }
    bool cand = any && (calc[idx] == 0);
    float oc = occ[idx];
    float qq = q[idx];
    bool nc = cand && ((oc - 0.5f) * (qq - 0.5f) < 0.0f);
    if (cand) {
        occ[idx] = qq;
        calc[idx] = 1;
    }
    cout[idx] = nc ? 1 : 0;
}

extern "C" void kernel_launch(void* const* d_in, const int* in_sizes, int n_in,
                              void* d_out, int out_size, void* d_ws, size_t ws_size,
                              hipStream_t stream) {
    const float* W1   = (const float*)d_in[0];
    const float* b1   = (const float*)d_in[1];
    const float* W2   = (const float*)d_in[2];
    const float* b2   = (const float*)d_in[3];
    const float* W3   = (const float*)d_in[4];
    const float* b3   = (const float*)d_in[5];
    const float* bmin = (const float*)d_in[6];
    const float* bmax = (const float*)d_in[7];

    const int RF = 513;
    const int NF = RF * RF;            // 263169

    float* qbuf = (float*)d_ws;
    float* occ0 = qbuf + NF;
    float* occ1 = occ0 + NF;
    u8* raw   = (u8*)(occ1 + NF);
    u8* calc0 = raw + NF;
    u8* calc1 = calc0 + NF;
    u8* confA = calc1 + NF;
    u8* confB = confA + NF;

    const int Rs[5] = {33, 65, 129, 257, 513};

    // base level: full MLP eval at 33x33, calc = all true
    {
        int R = Rs[0];
        int N = R * R;
        int nb = (N + 255) / 256;
        eval_grid_kernel<<<nb, 256, 0, stream>>>(W1, b1, W2, b2, W3, b3, bmin, bmax, occ0, R);
        hipMemsetAsync(calc0, 1, (size_t)N, stream);
    }

    const float* occPrev = occ0;
    const u8*    calcPrev = calc0;
    float* occBufs[2]  = {occ1, occ0};
    u8*    calcBufs[2] = {calc1, calc0};

    for (int l = 1; l < 5; l++) {
        int R  = Rs[l];
        int Rp = Rs[l - 1];
        int N  = R * R;
        int nb = (N + 255) / 256;
        float* occDst = (l == 4) ? (float*)d_out : occBufs[(l - 1) & 1];
        u8*    calcDst = calcBufs[(l - 1) & 1];

        eval_grid_kernel<<<nb, 256, 0, stream>>>(W1, b1, W2, b2, W3, b3, bmin, bmax, qbuf, R);
        init_level_kernel<<<nb, 256, 0, stream>>>(occPrev, Rp, occDst, raw, R);
        boundary_resolve_kernel<<<nb, 256, 0, stream>>>(raw, calcPrev, Rp, qbuf, occDst, calcDst, confA, R);
        conflict_iter_kernel<<<nb, 256, 0, stream>>>(confA, confB, calcDst, qbuf, occDst, R);
        conflict_iter_kernel<<<nb, 256, 0, stream>>>(confB, confA, calcDst, qbuf, occDst, R);
        conflict_iter_kernel<<<nb, 256, 0, stream>>>(confA, confB, calcDst, qbuf, occDst, R);

        occPrev = occDst;
        calcPrev = calcDst;
    }
}

// Round 2
// 429.390 us; speedup vs baseline: 2.4783x; 2.4783x over previous
//
#include <hip/hip_runtime.h>

typedef unsigned char u8;
typedef short short8 __attribute__((ext_vector_type(8)));
typedef float f32x4 __attribute__((ext_vector_type(4)));

#define DIM 128
#define TM  128
// LDS layout (bytes):
//   Ahi [0,32768)  Alo [32768,65536)  Bhi [65536,98304)  Blo [98304,131072)
//   H2 (f32 128x128) reuses [0,65536) after MFMA phase (barriers separate uses)
// All tiles stored as 16B chunks, chunk index XOR-swizzled with (row&7) ->
// every ds_read_b128 / ds_write_b128 in this kernel is bank-conflict-optimal.
#define SMEM_BYTES 131072

__device__ __forceinline__ unsigned short f2bf(float f) {
    unsigned u = __builtin_bit_cast(unsigned, f);
    u = (u + 0x7FFFu + ((u >> 16) & 1u)) >> 16;   // RNE
    return (unsigned short)u;
}
__device__ __forceinline__ float bf2f(unsigned short b) {
    unsigned u = ((unsigned)b) << 16;
    return __builtin_bit_cast(float, u);
}

// Fused MLP grid eval: layer1(tanh) -> split-bf16 MFMA GEMM -> tanh -> W3 dot -> sigmoid
__global__ __launch_bounds__(256) void eval_grid_mfma(
    const float* __restrict__ W1, const float* __restrict__ b1,
    const float* __restrict__ W2, const float* __restrict__ b2,
    const float* __restrict__ W3, const float* __restrict__ b3,
    const float* __restrict__ bmin, const float* __restrict__ bmax,
    float* __restrict__ out, int R)
{
    extern __shared__ char smem[];
    short8* Ahi = (short8*)smem;              // [128 rows][16 chunks]
    short8* Alo = (short8*)(smem + 32768);
    short8* Bhi = (short8*)(smem + 65536);    // Bt[n][k] : row=n, 16 k-chunks
    short8* Blo = (short8*)(smem + 98304);
    float*  H2  = (float*)smem;               // [128][128] f32, swizzled chunks

    const int tid = threadIdx.x;
    const int N = R * R;
    const int m0 = blockIdx.x * TM;
    const float inv = 1.0f / (float)(R - 1);  // R-1 power of two -> exact
    const float bx0 = bmin[0], by0 = bmin[1];
    const float sx = bmax[0] - bx0, sy = bmax[1] - by0;

    // ---------------- stage W2 -> Bt (transposed, hi/lo split) ----------------
    #pragma unroll
    for (int s = 0; s < 8; ++s) {
        int c  = s * 256 + tid;       // chunk id 0..2047
        int n  = c & 127;             // output dim (Bt row)
        int ko = c >> 7;              // k-octet 0..15
        short8 vh, vl;
        #pragma unroll
        for (int q = 0; q < 8; ++q) {
            float wv = W2[(ko * 8 + q) * DIM + n];   // coalesced over n
            unsigned short hb = f2bf(wv);
            vh[q] = (short)hb;
            vl[q] = (short)f2bf(wv - bf2f(hb));
        }
        int sw = ko ^ (n & 7);
        Bhi[n * 16 + sw] = vh;
        Blo[n * 16 + sw] = vl;
    }

    // ---------------- layer 1: h1 = tanh(pts@W1 + b1), split to LDS ----------
    const int p  = tid >> 1;          // point row 0..127
    const int hh = tid & 1;           // which 64-dim half
    const int pi = m0 + p;
    const int pg = (pi < N) ? pi : 0; // dummy coords for tail rows
    const int gi = pg / R, gj = pg - gi * R;
    const float x = bx0 + (float)gj * inv * sx;
    const float y = by0 + (float)gi * inv * sy;
    #pragma unroll
    for (int ko8 = 0; ko8 < 8; ++ko8) {
        short8 vh, vl;
        #pragma unroll
        for (int q = 0; q < 8; ++q) {
            int d = hh * 64 + ko8 * 8 + q;
            float pre = x * W1[d] + y * W1[DIM + d] + b1[d];
            float h = tanhf(pre);
            unsigned short hb = f2bf(h);
            vh[q] = (short)hb;
            vl[q] = (short)f2bf(h - bf2f(hb));
        }
        int chunk = hh * 8 + ko8;
        int sw = chunk ^ (p & 7);
        Ahi[p * 16 + sw] = vh;
        Alo[p * 16 + sw] = vl;
    }
    __syncthreads();

    // ---------------- MFMA: H2pre = H1 @ W2 (3-term split-bf16) --------------
    const int w    = tid >> 6;        // wave 0..3 -> 2x2 grid of 64x64 tiles
    const int lane = tid & 63;
    const int wr = w >> 1, wc = w & 1;
    const int l15 = lane & 15, lg = lane >> 4;

    f32x4 acc[4][4];
    #pragma unroll
    for (int mf = 0; mf < 4; ++mf)
        #pragma unroll
        for (int nf = 0; nf < 4; ++nf)
            acc[mf][nf] = (f32x4)(0.0f);

    #pragma unroll
    for (int kf = 0; kf < 4; ++kf) {
        const int ck = kf * 4 + lg;   // 16B chunk along K (8 bf16 per chunk)
        short8 ah[4], al[4], bh[4], bl[4];
        #pragma unroll
        for (int mf = 0; mf < 4; ++mf) {
            int r = wr * 64 + mf * 16 + l15;          // A row = lane&15
            int sw = ck ^ (r & 7);
            ah[mf] = Ahi[r * 16 + sw];
            al[mf] = Alo[r * 16 + sw];
        }
        #pragma unroll
        for (int nf = 0; nf < 4; ++nf) {
            int cc = wc * 64 + nf * 16 + l15;         // B col = lane&15
            int sw = ck ^ (cc & 7);
            bh[nf] = Bhi[cc * 16 + sw];
            bl[nf] = Blo[cc * 16 + sw];
        }
        #pragma unroll
        for (int mf = 0; mf < 4; ++mf)
            #pragma unroll
            for (int nf = 0; nf < 4; ++nf) {
                acc[mf][nf] = __builtin_amdgcn_mfma_f32_16x16x32_bf16(ah[mf], bh[nf], acc[mf][nf], 0, 0, 0);
                acc[mf][nf] = __builtin_amdgcn_mfma_f32_16x16x32_bf16(ah[mf], bl[nf], acc[mf][nf], 0, 0, 0);
                acc[mf][nf] = __builtin_amdgcn_mfma_f32_16x16x32_bf16(al[mf], bh[nf], acc[mf][nf], 0, 0, 0);
            }
    }
    __syncthreads();   // all waves done reading A region before H2 overwrites it

    // ---------------- spill H2pre to LDS (C/D: row=(lg)*4+reg, col=l15) ------
    #pragma unroll
    for (int mf = 0; mf < 4; ++mf) {
        #pragma unroll
        for (int nf = 0; nf < 4; ++nf) {
            int cc = wc * 64 + nf * 16 + l15;
            int lc = cc >> 2;
            #pragma unroll
            for (int rg = 0; rg < 4; ++rg) {
                int r = wr * 64 + mf * 16 + lg * 4 + rg;
                int word = r * 128 + ((lc ^ (r & 7)) << 2) + (cc & 3);
                H2[word] = acc[mf][nf][rg];
            }
        }
    }
    __syncthreads();

    // ---------------- epilogue: tanh, dot W3, sigmoid ------------------------
    float ssum = 0.0f;
    #pragma unroll
    for (int t = 0; t < 16; ++t) {
        int lc = hh * 16 + t;
        int word = p * 128 + ((lc ^ (p & 7)) << 2);
        f32x4 v = *(const f32x4*)&H2[word];
        #pragma unroll
        for (int q = 0; q < 4; ++q) {
            int d = lc * 4 + q;
            ssum += tanhf(v[q] + b2[d]) * W3[d];
        }
    }
    ssum += __shfl_xor(ssum, 1);      // combine the two 64-dim halves
    if (hh == 0 && pi < N) {
        float o = ssum + b3[0];
        out[pi] = 1.0f / (1.0f + expf(-o));
    }
}

// ------------- per level: exact 2x-1 bilinear upsample + raw boundary --------
__global__ __launch_bounds__(256) void init_level_kernel(
    const float* __restrict__ occP, int Rp,
    float* __restrict__ occI, u8* __restrict__ raw, int R)
{
    int idx = blockIdx.x * blockDim.x + threadIdx.x;
    int N = R * R;
    if (idx >= N) return;
    int i = idx / R;
    int j = idx - i * R;
    int ip = i >> 1, jp = j >> 1;
    const float BAL = 0.5f;
    float tl = occP[ip * Rp + jp];
    float val; bool b;
    int oi = i & 1, oj = j & 1;
    if (!oi && !oj) {
        val = tl; b = false;
    } else if (oi && !oj) {
        float bl = occP[(ip + 1) * Rp + jp];
        val = 0.5f * (tl + bl);
        b = (tl > BAL) != (bl > BAL);
    } else if (!oi && oj) {
        float tr = occP[ip * Rp + jp + 1];
        val = 0.5f * (tl + tr);
        b = (tl > BAL) != (tr > BAL);
    } else {
        float bl = occP[(ip + 1) * Rp + jp];
        float tr = occP[ip * Rp + jp + 1];
        float br = occP[(ip + 1) * Rp + jp + 1];
        val = 0.5f * (0.5f * (tl + bl) + 0.5f * (tr + br));  // exact _up2 order
        bool m0 = tl > BAL, m1 = bl > BAL, m2 = tr > BAL, m3 = br > BAL;
        b = (m0 | m1 | m2 | m3) && !(m0 & m1 & m2 & m3);
    }
    occI[idx] = val;
    raw[idx] = b ? 1 : 0;
}

// ------- boundary = any3x3(raw) & ~calc ; conflicts ; occ select ; calc ------
__global__ __launch_bounds__(256) void boundary_resolve_kernel(
    const u8* __restrict__ raw, const u8* __restrict__ calcP, int Rp,
    const float* __restrict__ q, float* __restrict__ occ,
    u8* __restrict__ calc, u8* __restrict__ conf, int R)
{
    int idx = blockIdx.x * blockDim.x + threadIdx.x;
    int N = R * R;
    if (idx >= N) return;
    int i = idx / R;
    int j = idx - i * R;
    bool b = false;
    for (int di = -1; di <= 1; di++) {
        int ii = i + di;
        if (ii < 0 || ii >= R) continue;
        for (int dj = -1; dj <= 1; dj++) {
            int jj = j + dj;
            if (jj < 0 || jj >= R) continue;
            if (raw[ii * R + jj]) b = true;
        }
    }
    bool c0 = (((i | j) & 1) == 0) ? (calcP[(i >> 1) * Rp + (j >> 1)] != 0) : false;
    b = b && !c0;
    float oi = occ[idx];
    float qq = q[idx];
    bool cf = b && ((oi - 0.5f) * (qq - 0.5f) < 0.0f);
    occ[idx] = b ? qq : oi;
    calc[idx] = (c0 || b) ? 1 : 0;
    conf[idx] = cf ? 1 : 0;
}

// --------------------- one conflict propagation iteration --------------------
__global__ __launch_bounds__(256) void conflict_iter_kernel(
    const u8* __restrict__ cin, u8* __restrict__ cout,
    u8* __restrict__ calc, const float* __restrict__ q,
    float* __restrict__ occ, int R)
{
    int idx = blockIdx.x * blockDim.x + threadIdx.x;
    int N = R * R;
    if (idx >= N) return;
    int i = idx / R;
    int j = idx - i * R;
    bool any = false;
    for (int di = -1; di <= 1; di++) {
        int ii = i + di;
        if (ii < 0 || ii >= R) continue;
        for (int dj = -1; dj <= 1; dj++) {
            int jj = j + dj;
            if (jj < 0 || jj >= R) continue;
            if (cin[ii * R + jj]) any = true;
        }
    }
    bool cand = any && (calc[idx] == 0);
    float oc = occ[idx];
    float qq = q[idx];
    bool nc = cand && ((oc - 0.5f) * (qq - 0.5f) < 0.0f);
    if (cand) {
        occ[idx] = qq;
        calc[idx] = 1;
    }
    cout[idx] = nc ? 1 : 0;
}

extern "C" void kernel_launch(void* const* d_in, const int* in_sizes, int n_in,
                              void* d_out, int out_size, void* d_ws, size_t ws_size,
                              hipStream_t stream) {
    const float* W1   = (const float*)d_in[0];
    const float* b1   = (const float*)d_in[1];
    const float* W2   = (const float*)d_in[2];
    const float* b2   = (const float*)d_in[3];
    const float* W3   = (const float*)d_in[4];
    const float* b3   = (const float*)d_in[5];
    const float* bmin = (const float*)d_in[6];
    const float* bmax = (const float*)d_in[7];

    const int RF = 513;
    const int NF = RF * RF;            // 263169

    float* qbuf = (float*)d_ws;
    float* occ0 = qbuf + NF;
    float* occ1 = occ0 + NF;
    u8* raw   = (u8*)(occ1 + NF);
    u8* calc0 = raw + NF;
    u8* calc1 = calc0 + NF;
    u8* confA = calc1 + NF;
    u8* confB = confA + NF;

    const int Rs[5] = {33, 65, 129, 257, 513};

    // base level: full MLP eval at 33x33, calc = all true
    {
        int R = Rs[0];
        int N = R * R;
        int nb = (N + TM - 1) / TM;
        eval_grid_mfma<<<nb, 256, SMEM_BYTES, stream>>>(W1, b1, W2, b2, W3, b3, bmin, bmax, occ0, R);
        hipMemsetAsync(calc0, 1, (size_t)N, stream);
    }

    const float* occPrev = occ0;
    const u8*    calcPrev = calc0;
    float* occBufs[2]  = {occ1, occ0};
    u8*    calcBufs[2] = {calc1, calc0};

    for (int l = 1; l < 5; l++) {
        int R  = Rs[l];
        int Rp = Rs[l - 1];
        int N  = R * R;
        int nb = (N + 255) / 256;
        int nbe = (N + TM - 1) / TM;
        float* occDst = (l == 4) ? (float*)d_out : occBufs[(l - 1) & 1];
        u8*    calcDst = calcBufs[(l - 1) & 1];

        eval_grid_mfma<<<nbe, 256, SMEM_BYTES, stream>>>(W1, b1, W2, b2, W3, b3, bmin, bmax, qbuf, R);
        init_level_kernel<<<nb, 256, 0, stream>>>(occPrev, Rp, occDst, raw, R);
        boundary_resolve_kernel<<<nb, 256, 0, stream>>>(raw, calcPrev, Rp, qbuf, occDst, calcDst, confA, R);
        conflict_iter_kernel<<<nb, 256, 0, stream>>>(confA, confB, calcDst, qbuf, occDst, R);
        conflict_iter_kernel<<<nb, 256, 0, stream>>>(confB, confA, calcDst, qbuf, occDst, R);
        conflict_iter_kernel<<<nb, 256, 0, stream>>>(confA, confB, calcDst, qbuf, occDst, R);

        occPrev = occDst;
        calcPrev = calcDst;
    }
}

// Round 3
// 173.583 us; speedup vs baseline: 6.1306x; 2.4737x over previous
//
#include <hip/hip_runtime.h>

typedef unsigned char u8;
typedef short short8 __attribute__((ext_vector_type(8)));
typedef float f32x4 __attribute__((ext_vector_type(4)));

#define DIM 128
#define TM  128
// eval LDS: Ahi[0,32K) Alo[32K,64K) Bhi[64K,96K) Blo[96K,128K) sPart[128K,+1K)
#define SMEM_BYTES 132096

__device__ __forceinline__ unsigned short f2bf(float f) {
    unsigned u = __builtin_bit_cast(unsigned, f);
    u = (u + 0x7FFFu + ((u >> 16) & 1u)) >> 16;   // RNE
    return (unsigned short)u;
}
__device__ __forceinline__ float bf2f(unsigned short b) {
    unsigned u = ((unsigned)b) << 16;
    return __builtin_bit_cast(float, u);
}
__device__ __forceinline__ float fast_tanh(float x) {
    // tanh(x) = 1 - 2/(exp2(2x*log2e)+1); exact +-1 saturation via inf/0
    float e = __builtin_amdgcn_exp2f(x * 2.885390081777927f);
    return 1.0f - 2.0f * __builtin_amdgcn_rcpf(e + 1.0f);
}
__device__ __forceinline__ float fast_sigmoid(float x) {
    float e = __builtin_amdgcn_exp2f(x * -1.4426950408889634f);
    return __builtin_amdgcn_rcpf(1.0f + e);
}

// ---- fused MLP eval for ALL 5 resolutions in one launch ----
// blocks: [0,9)->R33, [9,43)->R65, [43,174)->R129, [174,691)->R257, [691,2748)->R513
__global__ __launch_bounds__(512) void eval_all_mfma(
    const float* __restrict__ W1, const float* __restrict__ b1,
    const float* __restrict__ W2, const float* __restrict__ b2,
    const float* __restrict__ W3, const float* __restrict__ b3,
    const float* __restrict__ bmin, const float* __restrict__ bmax,
    float* __restrict__ q0, float* __restrict__ q1, float* __restrict__ q2,
    float* __restrict__ q3, float* __restrict__ q4)
{
    extern __shared__ char smem[];
    short8* Ahi = (short8*)smem;              // [128 rows][16 chunks], swizzled
    short8* Alo = (short8*)(smem + 32768);
    short8* Bhi = (short8*)(smem + 65536);    // Bt[n][k-chunk], swizzled
    short8* Blo = (short8*)(smem + 98304);
    float*  sPart = (float*)(smem + 131072);  // [128 rows][2 halves]

    const int tid = threadIdx.x;
    const int bid = blockIdx.x;
    int R, m0; float* out;
    if      (bid < 9)   { R = 33;  out = q0; m0 = bid * TM; }
    else if (bid < 43)  { R = 65;  out = q1; m0 = (bid - 9) * TM; }
    else if (bid < 174) { R = 129; out = q2; m0 = (bid - 43) * TM; }
    else if (bid < 691) { R = 257; out = q3; m0 = (bid - 174) * TM; }
    else                { R = 513; out = q4; m0 = (bid - 691) * TM; }
    const int N = R * R;

    // ---- stage W2 -> Bt (transposed, hi/lo bf16 split) ----
    #pragma unroll
    for (int s = 0; s < 4; ++s) {
        int c  = s * 512 + tid;       // chunk 0..2047
        int n  = c & 127;
        int ko = c >> 7;
        short8 vh, vl;
        #pragma unroll
        for (int qq = 0; qq < 8; ++qq) {
            float wv = W2[(ko * 8 + qq) * DIM + n];
            unsigned short hb = f2bf(wv);
            vh[qq] = (short)hb;
            vl[qq] = (short)f2bf(wv - bf2f(hb));
        }
        int sw = ko ^ (n & 7);
        Bhi[n * 16 + sw] = vh;
        Blo[n * 16 + sw] = vl;
    }

    // ---- layer 1: h1 = tanh(pts@W1+b1), hi/lo split to LDS ----
    const int p  = tid >> 2;          // point row 0..127
    const int qt = tid & 3;           // 32-dim quarter
    const int pi = m0 + p;
    const int pg = (pi < N) ? pi : N - 1;
    const int gi = pg / R, gj = pg - gi * R;
    const float inv = 1.0f / (float)(R - 1);   // R-1 pow2 -> exact
    const float x = bmin[0] + (float)gj * inv * (bmax[0] - bmin[0]);
    const float y = bmin[1] + (float)gi * inv * (bmax[1] - bmin[1]);
    #pragma unroll
    for (int co = 0; co < 4; ++co) {
        int ch = qt * 4 + co;         // k-octet 0..15
        short8 vh, vl;
        #pragma unroll
        for (int qq = 0; qq < 8; ++qq) {
            int d = ch * 8 + qq;
            float pre = fmaf(x, W1[d], fmaf(y, W1[DIM + d], b1[d]));
            float h = fast_tanh(pre);
            unsigned short hb = f2bf(h);
            vh[qq] = (short)hb;
            vl[qq] = (short)f2bf(h - bf2f(hb));
        }
        int sw = ch ^ (p & 7);
        Ahi[p * 16 + sw] = vh;
        Alo[p * 16 + sw] = vl;
    }
    __syncthreads();

    // ---- MFMA: H2pre = H1 @ W2, 3-term split-bf16 ----
    const int w = tid >> 6, lane = tid & 63;
    const int wr = w >> 1, wc = w & 1;           // 4x2 wave grid: 32x64 out/wave
    const int l15 = lane & 15, lg = lane >> 4;

    f32x4 acc[2][4];
    #pragma unroll
    for (int mf = 0; mf < 2; ++mf)
        #pragma unroll
        for (int nf = 0; nf < 4; ++nf) acc[mf][nf] = (f32x4)(0.0f);

    #pragma unroll
    for (int kf = 0; kf < 4; ++kf) {
        const int ck = kf * 4 + lg;
        short8 ah[2], al[2], bh[4], bl[4];
        #pragma unroll
        for (int mf = 0; mf < 2; ++mf) {
            int r = wr * 32 + mf * 16 + l15;
            int sw = ck ^ (r & 7);
            ah[mf] = Ahi[r * 16 + sw];
            al[mf] = Alo[r * 16 + sw];
        }
        #pragma unroll
        for (int nf = 0; nf < 4; ++nf) {
            int cc = wc * 64 + nf * 16 + l15;
            int sw = ck ^ (cc & 7);
            bh[nf] = Bhi[cc * 16 + sw];
            bl[nf] = Blo[cc * 16 + sw];
        }
        #pragma unroll
        for (int mf = 0; mf < 2; ++mf)
            #pragma unroll
            for (int nf = 0; nf < 4; ++nf) {
                acc[mf][nf] = __builtin_amdgcn_mfma_f32_16x16x32_bf16(ah[mf], bh[nf], acc[mf][nf], 0, 0, 0);
                acc[mf][nf] = __builtin_amdgcn_mfma_f32_16x16x32_bf16(ah[mf], bl[nf], acc[mf][nf], 0, 0, 0);
                acc[mf][nf] = __builtin_amdgcn_mfma_f32_16x16x32_bf16(al[mf], bh[nf], acc[mf][nf], 0, 0, 0);
            }
    }

    // ---- epilogue in registers: tanh(h2+b2)*W3, row-reduce via shfl ----
    // C/D layout: row = wr*32+mf*16+lg*4+rg, col = wc*64+nf*16+l15
    float rs[2][4] = {{0,0,0,0},{0,0,0,0}};
    #pragma unroll
    for (int mf = 0; mf < 2; ++mf)
        #pragma unroll
        for (int nf = 0; nf < 4; ++nf) {
            int c = wc * 64 + nf * 16 + l15;
            float w3v = W3[c], b2v = b2[c];
            #pragma unroll
            for (int rg = 0; rg < 4; ++rg)
                rs[mf][rg] += fast_tanh(acc[mf][nf][rg] + b2v) * w3v;
        }
    #pragma unroll
    for (int mf = 0; mf < 2; ++mf)
        #pragma unroll
        for (int rg = 0; rg < 4; ++rg) {
            float v = rs[mf][rg];
            v += __shfl_xor(v, 1);
            v += __shfl_xor(v, 2);
            v += __shfl_xor(v, 4);
            v += __shfl_xor(v, 8);
            rs[mf][rg] = v;
        }
    if (l15 == 0) {
        #pragma unroll
        for (int mf = 0; mf < 2; ++mf)
            #pragma unroll
            for (int rg = 0; rg < 4; ++rg)
                sPart[(wr * 32 + mf * 16 + lg * 4 + rg) * 2 + wc] = rs[mf][rg];
    }
    __syncthreads();
    if (tid < 128) {
        int po = m0 + tid;
        if (po < N) {
            float o = sPart[tid * 2] + sPart[tid * 2 + 1] + b3[0];
            out[po] = fast_sigmoid(o);
        }
    }
}

// ---- fused per-level: upsample + raw + boundary/resolve + 3 conflict iters ----
#define TS 32
#define HW 40   // TS + 2*4 halo
__global__ __launch_bounds__(256) void level_kernel(
    const float* __restrict__ occP, const u8* __restrict__ calcP, int Rp,
    const float* __restrict__ q, float* __restrict__ occOut,
    u8* __restrict__ calcOut, int R)
{
    __shared__ float sOcc[HW * HW], sQ[HW * HW];
    __shared__ u8 sRaw[HW * HW], sCalc[HW * HW], sCfA[HW * HW], sCfB[HW * HW];
    const int nT = (R + TS - 1) / TS;
    const int bi = blockIdx.x / nT, bj = blockIdx.x - bi * nT;
    const int fi0 = bi * TS - 4, fj0 = bj * TS - 4;
    const int tid = threadIdx.x;
    const float BAL = 0.5f;

    // phase 1: occ-interp + raw + c0 + q for the whole 40x40 region
    for (int c = tid; c < HW * HW; c += 256) {
        int li = c / HW, lj = c - li * HW;
        int fi = fi0 + li, fj = fj0 + lj;
        float occi = 0.5f, qv = 0.5f; u8 rw = 0, cal = 0;
        if (fi >= 0 && fi < R && fj >= 0 && fj < R) {
            int ip = fi >> 1, jp = fj >> 1;
            float tl = occP[ip * Rp + jp];
            int oi = fi & 1, oj = fj & 1;
            bool b;
            if (!oi && !oj) { occi = tl; b = false; }
            else if (oi && !oj) {
                float bl = occP[(ip + 1) * Rp + jp];
                occi = 0.5f * (tl + bl);
                b = (tl > BAL) != (bl > BAL);
            } else if (!oi && oj) {
                float tr = occP[ip * Rp + jp + 1];
                occi = 0.5f * (tl + tr);
                b = (tl > BAL) != (tr > BAL);
            } else {
                float bl = occP[(ip + 1) * Rp + jp];
                float tr = occP[ip * Rp + jp + 1];
                float br = occP[(ip + 1) * Rp + jp + 1];
                occi = 0.5f * (0.5f * (tl + bl) + 0.5f * (tr + br)); // exact _up2 order
                bool m0 = tl > BAL, m1 = bl > BAL, m2 = tr > BAL, m3 = br > BAL;
                b = (m0 | m1 | m2 | m3) && !(m0 & m1 & m2 & m3);
            }
            rw = b ? 1 : 0;
            if (((fi | fj) & 1) == 0) cal = calcP ? calcP[ip * Rp + jp] : 1;
            qv = q[fi * R + fj];
        }
        sOcc[c] = occi; sQ[c] = qv; sRaw[c] = rw; sCalc[c] = cal;
        sCfA[c] = 0; sCfB[c] = 0;
    }
    __syncthreads();

    // phase 2: boundary = any3x3(raw) & ~c0; conflicts0; occ select  (valid +-3)
    for (int c = tid; c < HW * HW; c += 256) {
        int li = c / HW, lj = c - li * HW;
        if (li < 1 || li >= HW - 1 || lj < 1 || lj >= HW - 1) continue;
        int fi = fi0 + li, fj = fj0 + lj;
        if (fi < 0 || fi >= R || fj < 0 || fj >= R) continue;
        bool b = false;
        #pragma unroll
        for (int di = -1; di <= 1; ++di)
            #pragma unroll
            for (int dj = -1; dj <= 1; ++dj)
                if (sRaw[(li + di) * HW + (lj + dj)]) b = true;
        b = b && !sCalc[c];
        float oi = sOcc[c], qq = sQ[c];
        u8 cf = (b && (oi - BAL) * (qq - BAL) < 0.0f) ? 1 : 0;
        if (b) { sOcc[c] = qq; sCalc[c] = 1; }
        sCfA[c] = cf;
    }
    __syncthreads();

    // 3 conflict-propagation iterations (valid regions shrink 2,3,4)
    for (int it = 0; it < 3; ++it) {
        const u8* cin = (it & 1) ? sCfB : sCfA;
        u8* cout      = (it & 1) ? sCfA : sCfB;
        int lo = 2 + it, hi = HW - 2 - it;
        for (int c = tid; c < HW * HW; c += 256) {
            int li = c / HW, lj = c - li * HW;
            if (li < lo || li >= hi || lj < lo || lj >= hi) continue;
            int fi = fi0 + li, fj = fj0 + lj;
            if (fi < 0 || fi >= R || fj < 0 || fj >= R) continue;
            bool any = false;
            #pragma unroll
            for (int di = -1; di <= 1; ++di)
                #pragma unroll
                for (int dj = -1; dj <= 1; ++dj)
                    if (cin[(li + di) * HW + (lj + dj)]) any = true;
            bool cand = any && !sCalc[c];
            float oc = sOcc[c], qq = sQ[c];
            u8 nc = (cand && (oc - BAL) * (qq - BAL) < 0.0f) ? 1 : 0;
            if (cand) { sOcc[c] = qq; sCalc[c] = 1; }
            cout[c] = nc;
        }
        __syncthreads();
    }

    // write core 32x32
    for (int c = tid; c < HW * HW; c += 256) {
        int li = c / HW, lj = c - li * HW;
        if (li < 4 || li >= HW - 4 || lj < 4 || lj >= HW - 4) continue;
        int fi = fi0 + li, fj = fj0 + lj;
        if (fi < 0 || fi >= R || fj < 0 || fj >= R) continue;
        occOut[fi * R + fj] = sOcc[c];
        calcOut[fi * R + fj] = sCalc[c];
    }
}

extern "C" void kernel_launch(void* const* d_in, const int* in_sizes, int n_in,
                              void* d_out, int out_size, void* d_ws, size_t ws_size,
                              hipStream_t stream) {
    const float* W1   = (const float*)d_in[0];
    const float* b1   = (const float*)d_in[1];
    const float* W2   = (const float*)d_in[2];
    const float* b2   = (const float*)d_in[3];
    const float* W3   = (const float*)d_in[4];
    const float* b3   = (const float*)d_in[5];
    const float* bmin = (const float*)d_in[6];
    const float* bmax = (const float*)d_in[7];

    const int N33 = 33 * 33, N65 = 65 * 65, N129 = 129 * 129,
              N257 = 257 * 257, N513 = 513 * 513;

    float* q0 = (float*)d_ws;
    float* q1 = q0 + N33;
    float* q2 = q1 + N65;
    float* q3 = q2 + N129;
    float* q4 = q3 + N257;
    float* occA = q4 + N513;
    float* occB = occA + N513;
    u8* calcA = (u8*)(occB + N513);
    u8* calcB = calcA + N513;

    // all 5 MLP grid evals in one launch (independent of each other)
    eval_all_mfma<<<2748, 512, SMEM_BYTES, stream>>>(
        W1, b1, W2, b2, W3, b3, bmin, bmax, q0, q1, q2, q3, q4);

    // level chain; base calc handled via calcP==nullptr (all-true)
    level_kernel<<<9,   256, 0, stream>>>(q0,   (const u8*)nullptr, 33,  q1, occA, calcB, 65);
    level_kernel<<<25,  256, 0, stream>>>(occA, calcB,              65,  q2, occB, calcA, 129);
    level_kernel<<<81,  256, 0, stream>>>(occB, calcA,              129, q3, occA, calcB, 257);
    level_kernel<<<289, 256, 0, stream>>>(occA, calcB,              257, q4, (float*)d_out, calcA, 513);
}